// Round 2
// baseline (166.000 us; speedup 1.0000x reference)
//
#include <hip/hip_runtime.h>
#include <math.h>

#define N_EMBD 512
#define N_HEAD 8
#define SEQ_T  2048
#define BATCH  4
#define QK_LD  1024

typedef __attribute__((ext_vector_type(8))) short bf16x8;  // 8 bf16 (4 VGPRs)
typedef __attribute__((ext_vector_type(4))) float f32x4;

#define CL 0.18033688f   // 0.125 * log2(e)

__device__ __forceinline__ unsigned short f2bf(float f) {
    union { float f; unsigned int u; } x; x.f = f;
    return (unsigned short)((x.u + 0x7FFFu + ((x.u >> 16) & 1u)) >> 16);  // RNE
}
// pack trunc-bf16(a) | trunc-bf16(b)<<16 in ONE v_perm
__device__ __forceinline__ unsigned pack_trunc(float a, float b) {
    union { float f; unsigned u; } x, y; x.f = a; y.f = b;
    return __builtin_amdgcn_perm(y.u, x.u, 0x07060302u);
}
// bf16x8 * scalar (unpack, mul, RNE repack) — once per block for Q
__device__ __forceinline__ bf16x8 scale_frag(bf16x8 v, float c) {
    bf16x8 r;
    #pragma unroll
    for (int i = 0; i < 8; ++i) {
        union { unsigned u; float f; } x;
        x.u = ((unsigned)(unsigned short)v[i]) << 16;
        r[i] = (short)f2bf(x.f * c);
    }
    return r;
}

// ---------------------------------------------------------------------------
// prep (weights only): [0,768) transpose attn_w ; [768,1024) proj_w
// ---------------------------------------------------------------------------
__global__ __launch_bounds__(256) void prep(
    const float* __restrict__ w1, unsigned short* __restrict__ w1t,
    const float* __restrict__ w2, unsigned short* __restrict__ w2t)
{
    __shared__ float t[32][33];
    const int bx = blockIdx.x, tid = threadIdx.x;
    const float* W; unsigned short* Wt; int N, tt, nb;
    if (bx < 768) { tt = bx;       W = w1; Wt = w1t; N = 1536; nb = 48; }
    else          { tt = bx - 768; W = w2; Wt = w2t; N = 512;  nb = 16; }
    const int n0 = (tt % nb) * 32, k0 = (tt / nb) * 32;
    const int tx = tid & 31, ty = tid >> 5;
    #pragma unroll
    for (int i = 0; i < 4; ++i)
        t[ty + i * 8][tx] = W[(size_t)(k0 + ty + i * 8) * N + n0 + tx];
    __syncthreads();
    #pragma unroll
    for (int i = 0; i < 4; ++i)
        Wt[(size_t)(n0 + ty + i * 8) * 512 + k0 + tx] = f2bf(t[tx][ty + i * 8]);
}

// ---------------------------------------------------------------------------
// MFMA GEMM (R9 body + XCD-local grid).
// OMODE: 0 = f32 C[row*N+col]; 1 = bf16 C[row*N+col];
//        2 = split QKV: col<1024 -> bf16 qk[row*1024+col],
//                       col>=1024 -> bf16 vT[(b*512 + col-1024)*2048 + t]
//            (b = row>>11, t = row&2047) — V written TRANSPOSED per (b,h,d).
// ---------------------------------------------------------------------------
template <int BM, int BN, bool CVT_A, int OMODE>
__global__ __launch_bounds__(256) void gemm_mfma(
    const void* __restrict__ Asrc,              // fp32 [M][K] if CVT_A else bf16
    const unsigned short* __restrict__ Bt,      // bf16 [N][K]
    const float* __restrict__ bias,
    void* __restrict__ C, unsigned short* __restrict__ Cv,
    int N, int K, int xcdRows)
{
    constexpr int WMT = BM / 32, WNT = BN / 32;
    constexpr int SA = BM * 8 / 256, SB = BN * 8 / 256;   // octs per thread
    __shared__ unsigned short As[BM * 64];
    __shared__ unsigned short Bs[BN * 64];

    const int tid  = threadIdx.x;
    const int wave = tid >> 6, lane = tid & 63;
    const int low  = lane & 15, quad = lane >> 4;
    const int wm   = (wave & 1) * (BM / 2), wn = (wave >> 1) * (BN / 2);

    const int xcd    = blockIdx.x & 7;
    const int within = blockIdx.x >> 3;
    const int rowBlk = xcd * xcdRows + (within % xcdRows);
    const int colBlk = within / xcdRows;
    const int row0 = rowBlk * BM, col0 = colBlk * BN;

    size_t a_src[SA]; int a_dst[SA];
    #pragma unroll
    for (int s = 0; s < SA; ++s) {
        const int p = tid + 256 * s;
        const int m = p >> 3, q = p & 7;
        a_src[s] = (size_t)(row0 + m) * K + q * 8;
        a_dst[s] = m * 64 + (q ^ (m & 7)) * 8;
    }
    size_t b_src[SB]; int b_dst[SB];
    #pragma unroll
    for (int s = 0; s < SB; ++s) {
        const int p = tid + 256 * s;
        const int m = p >> 3, q = p & 7;
        b_src[s] = (size_t)(col0 + m) * K + q * 8;
        b_dst[s] = m * 64 + (q ^ (m & 7)) * 8;
    }

    f32x4 acc[WMT][WNT];
    #pragma unroll
    for (int i = 0; i < WMT; ++i)
        #pragma unroll
        for (int j = 0; j < WNT; ++j) acc[i][j] = (f32x4){0.f, 0.f, 0.f, 0.f};

    bf16x8 ar[SA], br[SB];
    const float*          af32 = (const float*)Asrc;
    const unsigned short* a16  = (const unsigned short*)Asrc;

    #pragma unroll
    for (int s = 0; s < SA; ++s) {
        if (CVT_A) {
            const float4 f0 = *(const float4*)(af32 + a_src[s]);
            const float4 f1 = *(const float4*)(af32 + a_src[s] + 4);
            union { uint4 v; bf16x8 h; } u;
            u.v.x = pack_trunc(f0.x, f0.y); u.v.y = pack_trunc(f0.z, f0.w);
            u.v.z = pack_trunc(f1.x, f1.y); u.v.w = pack_trunc(f1.z, f1.w);
            ar[s] = u.h;
        } else {
            ar[s] = *(const bf16x8*)(a16 + a_src[s]);
        }
    }
    #pragma unroll
    for (int s = 0; s < SB; ++s) br[s] = *(const bf16x8*)(Bt + b_src[s]);

    const int NIT = K >> 6;
    for (int it = 0; it < NIT; ++it) {
        __syncthreads();
        #pragma unroll
        for (int s = 0; s < SA; ++s) *(bf16x8*)&As[a_dst[s]] = ar[s];
        #pragma unroll
        for (int s = 0; s < SB; ++s) *(bf16x8*)&Bs[b_dst[s]] = br[s];
        __syncthreads();

        if (it + 1 < NIT) {
            const int ko = (it + 1) * 64;
            #pragma unroll
            for (int s = 0; s < SA; ++s) {
                if (CVT_A) {
                    const float4 f0 = *(const float4*)(af32 + a_src[s] + ko);
                    const float4 f1 = *(const float4*)(af32 + a_src[s] + ko + 4);
                    union { uint4 v; bf16x8 h; } u;
                    u.v.x = pack_trunc(f0.x, f0.y); u.v.y = pack_trunc(f0.z, f0.w);
                    u.v.z = pack_trunc(f1.x, f1.y); u.v.w = pack_trunc(f1.z, f1.w);
                    ar[s] = u.h;
                } else {
                    ar[s] = *(const bf16x8*)(a16 + a_src[s] + ko);
                }
            }
            #pragma unroll
            for (int s = 0; s < SB; ++s) br[s] = *(const bf16x8*)(Bt + b_src[s] + ko);
        }

        #pragma unroll
        for (int h = 0; h < 2; ++h) {
            bf16x8 af[WMT], bfr[WNT];
            #pragma unroll
            for (int t = 0; t < WMT; ++t)
                af[t] = *(const bf16x8*)
                    &As[(wm + t * 16 + low) * 64 + (((h * 4 + quad) ^ (low & 7)) * 8)];
            #pragma unroll
            for (int t = 0; t < WNT; ++t)
                bfr[t] = *(const bf16x8*)
                    &Bs[(wn + t * 16 + low) * 64 + (((h * 4 + quad) ^ (low & 7)) * 8)];
            #pragma unroll
            for (int i = 0; i < WMT; ++i)
                #pragma unroll
                for (int j = 0; j < WNT; ++j)
                    acc[i][j] = __builtin_amdgcn_mfma_f32_16x16x32_bf16(
                        af[i], bfr[j], acc[i][j], 0, 0, 0);
        }
    }

    float bv[WNT];
    #pragma unroll
    for (int j = 0; j < WNT; ++j) bv[j] = bias[col0 + wn + j * 16 + low];
    const bool isV = (OMODE == 2) && (col0 >= 1024);
    #pragma unroll
    for (int i = 0; i < WMT; ++i)
        #pragma unroll
        for (int r = 0; r < 4; ++r) {
            const int row = row0 + wm + i * 16 + quad * 4 + r;
            #pragma unroll
            for (int j = 0; j < WNT; ++j) {
                const int col = col0 + wn + j * 16 + low;
                const float v = acc[i][j][r] + bv[j];
                if (OMODE == 0) {
                    ((float*)C)[(size_t)row * N + col] = v;
                } else if (OMODE == 1) {
                    ((unsigned short*)C)[(size_t)row * N + col] = f2bf(v);
                } else {
                    if (isV)
                        Cv[((size_t)((row >> 11) * 512 + col - 1024) << 11)
                           + (row & 2047)] = f2bf(v);
                    else
                        ((unsigned short*)C)[(size_t)row * QK_LD + col] = f2bf(v);
                }
            }
        }
}

// ---------------------------------------------------------------------------
// attention v3: wave-split-K, P-in-registers, ZERO LDS in the main loop.
//   waves: kh = wave&1 owns a 32-key slice; qh = wave>>1 owns 32 q-rows/side.
//   K: global->reg with PERMUTED rows (row = (low>>2)*8 + kt*4 + (low&3)) so
//      the two QK outputs (kt=0,1) ARE the K=32 PV A-fragment in-lane:
//      lane(low=q, quad), elem j holds P[q][k = kh*32 + quad*8 + j].
//   V: read from the TRANSPOSED vT buffer (written by gemm1) — the PV
//      B-fragment V[k=koffb+j][d=t*16+low] is 8 CONSECUTIVE k at fixed d
//      = one contiguous bf16x8 load per t. No LDS staging, no tr_read.
//   Epilogue: one cross-wave (kh0+kh1) o/l reduction through LDS.
// ---------------------------------------------------------------------------
template<bool MASK>
__device__ __forceinline__ void qk_step(
    const bf16x8 k00, const bf16x8 k01, const bf16x8 k10, const bf16x8 k11,
    const bf16x8 (&qf)[2][2], bf16x8 (&pf)[2], float (&lp)[2],
    const int qrel0, const int koffb)
{
    #pragma unroll
    for (int qb = 0; qb < 2; ++qb) {
        f32x4 s0 = (f32x4){0.f, 0.f, 0.f, 0.f};
        f32x4 s1 = (f32x4){0.f, 0.f, 0.f, 0.f};
        s0 = __builtin_amdgcn_mfma_f32_16x16x32_bf16(k00, qf[qb][0], s0, 0, 0, 0);
        s0 = __builtin_amdgcn_mfma_f32_16x16x32_bf16(k01, qf[qb][1], s0, 0, 0, 0);
        s1 = __builtin_amdgcn_mfma_f32_16x16x32_bf16(k10, qf[qb][0], s1, 0, 0, 0);
        s1 = __builtin_amdgcn_mfma_f32_16x16x32_bf16(k11, qf[qb][1], s1, 0, 0, 0);
        float p[8];
        #pragma unroll
        for (int r = 0; r < 4; ++r) {
            float v0 = s0[r], v1 = s1[r];
            if (MASK) {
                const int qrel = qrel0 + qb * 16;
                if (koffb + r     > qrel) v0 = -1e30f;   // exp2 -> 0
                if (koffb + r + 4 > qrel) v1 = -1e30f;
            }
            p[r]     = __builtin_amdgcn_exp2f(v0);
            p[r + 4] = __builtin_amdgcn_exp2f(v1);
        }
        // truncate to the exact bf16 values used by the PV MFMA, so l == sum(P_bf16)
        #pragma unroll
        for (int e = 0; e < 8; ++e) {
            union { float f; unsigned u; } c; c.f = p[e];
            c.u &= 0xFFFF0000u; p[e] = c.f;
        }
        lp[qb] += ((p[0] + p[1]) + (p[2] + p[3])) + ((p[4] + p[5]) + (p[6] + p[7]));
        union { uint4 v; bf16x8 h; } u;
        u.v.x = pack_trunc(p[0], p[1]); u.v.y = pack_trunc(p[2], p[3]);
        u.v.z = pack_trunc(p[4], p[5]); u.v.w = pack_trunc(p[6], p[7]);
        pf[qb] = u.h;
    }
}

__global__ __launch_bounds__(256, 2) void attn_mfma(
    const unsigned short* __restrict__ qk,    // bf16 [8192][1024]  (Q | K)
    const unsigned short* __restrict__ vT,    // bf16 [4*512][2048] (V transposed)
    unsigned short* __restrict__ y)           // bf16 [8192][512]
{
    const int bh  = blockIdx.x & 31;          // same-bh blocks -> same XCD
    const int pa  = blockIdx.x >> 5;          // 0..15
    const int b   = bh >> 3, h = bh & 7;
    const int qA0 = pa * 64;
    const int qB0 = (31 - pa) * 64;
    const int nA  = pa + 1, nB = 32 - pa;
    const int tid = threadIdx.x;
    const int wave = tid >> 6, lane = tid & 63;
    const int low  = lane & 15, quad = lane >> 4;
    const int kh   = wave & 1, qh = wave >> 1;

    __shared__ float oBuf[2][64 * 66];        // kh1 partials (stride 66)
    __shared__ float lBuf[2][2][64];          // [kh][qh][(s*2+qb)*16 + q16]

    const size_t base = (size_t)b * SEQ_T * QK_LD + h * 64;
    const unsigned short* qp = qk + base;
    const unsigned short* kp = qk + base + 512;
    const unsigned short* vp = vT + ((size_t)(b * 512 + h * 64) << 11);

    // Q fragments [side][qb][dh], scaled once
    bf16x8 qf[2][2][2];
    #pragma unroll
    for (int s = 0; s < 2; ++s) {
        const int q0 = (s ? qB0 : qA0) + qh * 32;
        #pragma unroll
        for (int qb = 0; qb < 2; ++qb) {
            const size_t qr = (size_t)(q0 + qb * 16 + low) * QK_LD;
            #pragma unroll
            for (int dh = 0; dh < 2; ++dh)
                qf[s][qb][dh] = scale_frag(
                    *(const bf16x8*)(qp + qr + dh * 32 + quad * 8), CL);
        }
    }

    // K register loads: permuted rows so QK outputs form the PV A-fragment
    const int rowperm = ((low >> 2) << 3) + (low & 3);           // +kt*4
    const unsigned short* kbase =
        kp + (size_t)(kh * 32 + rowperm) * QK_LD + quad * 8;
    const int koffb = kh * 32 + quad * 8;                        // lane's k base
    const unsigned short* vrow = vp + (size_t)low * SEQ_T + koffb;

    // prologue: tile 0 into regs
    bf16x8 kk[4], vv[4];
    kk[0] = *(const bf16x8*)(kbase);
    kk[1] = *(const bf16x8*)(kbase + 32);
    kk[2] = *(const bf16x8*)(kbase + 4 * QK_LD);
    kk[3] = *(const bf16x8*)(kbase + 4 * QK_LD + 32);
    #pragma unroll
    for (int t = 0; t < 4; ++t)
        vv[t] = *(const bf16x8*)(vrow + (size_t)(t * 16) * SEQ_T);

    f32x4 o[2][2][4];
    #pragma unroll
    for (int s = 0; s < 2; ++s)
        #pragma unroll
        for (int qb = 0; qb < 2; ++qb)
            #pragma unroll
            for (int t = 0; t < 4; ++t) o[s][qb][t] = (f32x4){0.f, 0.f, 0.f, 0.f};
    float lp[2][2] = {{0.f, 0.f}, {0.f, 0.f}};

    for (int kc = 0; kc < nB; ++kc) {
        bf16x8 nk[4], nv[4];
        const bool pfch = (kc + 1 < nB);
        if (pfch) {
            const unsigned short* kb = kbase + (size_t)(kc + 1) * (64 * QK_LD);
            nk[0] = *(const bf16x8*)(kb);
            nk[1] = *(const bf16x8*)(kb + 32);
            nk[2] = *(const bf16x8*)(kb + 4 * QK_LD);
            nk[3] = *(const bf16x8*)(kb + 4 * QK_LD + 32);
            const unsigned short* vb = vrow + (kc + 1) * 64;
            #pragma unroll
            for (int t = 0; t < 4; ++t)
                nv[t] = *(const bf16x8*)(vb + (size_t)(t * 16) * SEQ_T);
        }

        const int kc64 = kc * 64;
        bf16x8 pA[2], pB[2];
        const bool doA = (kc < nA);
        if (doA) {
            const int qrelA = qA0 + qh * 32 + low - kc64;
            if (kc == nA - 1)
                qk_step<true >(kk[0], kk[1], kk[2], kk[3], qf[0], pA, lp[0], qrelA, koffb);
            else
                qk_step<false>(kk[0], kk[1], kk[2], kk[3], qf[0], pA, lp[0], qrelA, koffb);
        }
        {
            const int qrelB = qB0 + qh * 32 + low - kc64;
            if (kc == nB - 1)
                qk_step<true >(kk[0], kk[1], kk[2], kk[3], qf[1], pB, lp[1], qrelB, koffb);
            else
                qk_step<false>(kk[0], kk[1], kk[2], kk[3], qf[1], pB, lp[1], qrelB, koffb);
        }

        if (doA) {
            #pragma unroll
            for (int t = 0; t < 4; ++t) {
                o[0][0][t] = __builtin_amdgcn_mfma_f32_16x16x32_bf16(pA[0], vv[t], o[0][0][t], 0, 0, 0);
                o[0][1][t] = __builtin_amdgcn_mfma_f32_16x16x32_bf16(pA[1], vv[t], o[0][1][t], 0, 0, 0);
            }
        }
        #pragma unroll
        for (int t = 0; t < 4; ++t) {
            o[1][0][t] = __builtin_amdgcn_mfma_f32_16x16x32_bf16(pB[0], vv[t], o[1][0][t], 0, 0, 0);
            o[1][1][t] = __builtin_amdgcn_mfma_f32_16x16x32_bf16(pB[1], vv[t], o[1][1][t], 0, 0, 0);
        }

        if (pfch) {
            #pragma unroll
            for (int t = 0; t < 4; ++t) { kk[t] = nk[t]; vv[t] = nv[t]; }
        }
    }

    // ---- epilogue: cross-wave (kh) reduction of o and l ----
    #pragma unroll
    for (int s = 0; s < 2; ++s)
        #pragma unroll
        for (int qb = 0; qb < 2; ++qb) {
            float v = lp[s][qb];
            v += __shfl_xor(v, 16);     // reduce over quads
            v += __shfl_xor(v, 32);
            if (quad == 0) lBuf[kh][qh][(s * 2 + qb) * 16 + low] = v;
        }
    if (kh == 1) {
        #pragma unroll
        for (int s = 0; s < 2; ++s)
            #pragma unroll
            for (int qb = 0; qb < 2; ++qb)
                #pragma unroll
                for (int t = 0; t < 4; ++t)
                    #pragma unroll
                    for (int r = 0; r < 4; ++r)
                        oBuf[qh][((s * 2 + qb) * 16 + quad * 4 + r) * 66 + low + t * 16]
                            = o[s][qb][t][r];
    }
    __syncthreads();
    if (kh == 0) {
        #pragma unroll
        for (int s = 0; s < 2; ++s) {
            const int q0 = (s ? qB0 : qA0) + qh * 32;
            #pragma unroll
            for (int qb = 0; qb < 2; ++qb) {
                #pragma unroll
                for (int r = 0; r < 4; ++r) {
                    const int ri = (s * 2 + qb) * 16 + quad * 4 + r;
                    const float l = lBuf[0][qh][ri] + lBuf[1][qh][ri];
                    const float rl = 1.f / l;
                    const int qrow = q0 + qb * 16 + quad * 4 + r;
                    unsigned short* yp =
                        y + (size_t)(b * SEQ_T + qrow) * N_EMBD + h * 64 + low;
                    #pragma unroll
                    for (int t = 0; t < 4; ++t)
                        yp[t * 16] = f2bf(
                            (o[s][qb][t][r] + oBuf[qh][ri * 66 + low + t * 16]) * rl);
                }
            }
        }
    }
}

// ---------------------------------------------------------------------------
extern "C" void kernel_launch(void* const* d_in, const int* in_sizes, int n_in,
                              void* d_out, int out_size, void* d_ws, size_t ws_size,
                              hipStream_t stream)
{
    const float* x      = (const float*)d_in[0];
    const float* attn_w = (const float*)d_in[1];   // [512][1536]
    const float* attn_b = (const float*)d_in[2];
    const float* proj_w = (const float*)d_in[3];   // [512][512]
    const float* proj_b = (const float*)d_in[4];
    float*       out    = (float*)d_out;

    char* ws = (char*)d_ws;
    unsigned short* qk_bf = (unsigned short*)(ws);                       // 16.78 MB
    unsigned short* vT    = (unsigned short*)(ws + 16777216);            //  8.39 MB
    unsigned short* y_bf  = (unsigned short*)(ws + 25165824);            //  8.39 MB
    unsigned short* w1t   = (unsigned short*)(ws + 33554432);            //  1.57 MB
    unsigned short* w2t   = (unsigned short*)(ws + 35127296);            //  0.52 MB

    prep<<<1024, 256, 0, stream>>>(attn_w, w1t, proj_w, w2t);

    // qkv = x(fp32, converted in-staging) @ w1t^T + b ; Q/K -> qk_bf, V -> vT
    gemm_mfma<128, 128, true, 2><<<dim3(768), 256, 0, stream>>>(
        x, w1t, attn_b, qk_bf, vT, 1536, N_EMBD, 8);

    attn_mfma<<<dim3(512), 256, 0, stream>>>(qk_bf, vT, y_bf);

    gemm_mfma<64, 128, false, 0><<<dim3(512), 256, 0, stream>>>(
        y_bf, w2t, proj_b, out, nullptr, N_EMBD, N_EMBD, 16);
}

// Round 3
// 134.673 us; speedup vs baseline: 1.2326x; 1.2326x over previous
//
#include <hip/hip_runtime.h>
#include <math.h>

#define N_EMBD 512
#define N_HEAD 8
#define SEQ_T  2048
#define BATCH  4
#define QK_LD  1024

typedef __attribute__((ext_vector_type(8))) short bf16x8;  // 8 bf16 (4 VGPRs)
typedef __attribute__((ext_vector_type(4))) float f32x4;

#define CL 0.18033688f   // 0.125 * log2(e)

__device__ __forceinline__ unsigned short f2bf(float f) {
    union { float f; unsigned int u; } x; x.f = f;
    return (unsigned short)((x.u + 0x7FFFu + ((x.u >> 16) & 1u)) >> 16);  // RNE
}
// pack trunc-bf16(a) | trunc-bf16(b)<<16 in ONE v_perm
__device__ __forceinline__ unsigned pack_trunc(float a, float b) {
    union { float f; unsigned u; } x, y; x.f = a; y.f = b;
    return __builtin_amdgcn_perm(y.u, x.u, 0x07060302u);
}
// bf16x8 * scalar (unpack, mul, RNE repack) — once per block for Q
__device__ __forceinline__ bf16x8 scale_frag(bf16x8 v, float c) {
    bf16x8 r;
    #pragma unroll
    for (int i = 0; i < 8; ++i) {
        union { unsigned u; float f; } x;
        x.u = ((unsigned)(unsigned short)v[i]) << 16;
        r[i] = (short)f2bf(x.f * c);
    }
    return r;
}

// async global->LDS, 16B per lane; dest = wave-uniform base + lane*16
__device__ __forceinline__ void gl_lds16(const void* g, void* s) {
    __builtin_amdgcn_global_load_lds(
        (const __attribute__((address_space(1))) void*)g,
        (__attribute__((address_space(3))) void*)s, 16, 0, 0);
}

// ---------------------------------------------------------------------------
// prep (weights only): [0,768) transpose attn_w ; [768,1024) proj_w
// ---------------------------------------------------------------------------
__global__ __launch_bounds__(256) void prep(
    const float* __restrict__ w1, unsigned short* __restrict__ w1t,
    const float* __restrict__ w2, unsigned short* __restrict__ w2t)
{
    __shared__ float t[32][33];
    const int bx = blockIdx.x, tid = threadIdx.x;
    const float* W; unsigned short* Wt; int N, tt, nb;
    if (bx < 768) { tt = bx;       W = w1; Wt = w1t; N = 1536; nb = 48; }
    else          { tt = bx - 768; W = w2; Wt = w2t; N = 512;  nb = 16; }
    const int n0 = (tt % nb) * 32, k0 = (tt / nb) * 32;
    const int tx = tid & 31, ty = tid >> 5;
    #pragma unroll
    for (int i = 0; i < 4; ++i)
        t[ty + i * 8][tx] = W[(size_t)(k0 + ty + i * 8) * N + n0 + tx];
    __syncthreads();
    #pragma unroll
    for (int i = 0; i < 4; ++i)
        Wt[(size_t)(n0 + ty + i * 8) * 512 + k0 + tx] = f2bf(t[tx][ty + i * 8]);
}

// ---------------------------------------------------------------------------
// MFMA GEMM (R9 body + XCD-local grid).
// OMODE: 0 = f32 C[row*N+col]; 1 = bf16 C[row*N+col];
//        2 = split QKV: col<1024 -> bf16 qk[row*1024+col];
//            col>=1024 (V) -> transpose tile through LDS, then COALESCED
//            16B stores to vT[(b*512 + col-1024)*2048 + t].
// ---------------------------------------------------------------------------
template <int BM, int BN, bool CVT_A, int OMODE>
__global__ __launch_bounds__(256) void gemm_mfma(
    const void* __restrict__ Asrc,              // fp32 [M][K] if CVT_A else bf16
    const unsigned short* __restrict__ Bt,      // bf16 [N][K]
    const float* __restrict__ bias,
    void* __restrict__ C, unsigned short* __restrict__ Cv,
    int N, int K, int xcdRows)
{
    constexpr int WMT = BM / 32, WNT = BN / 32;
    constexpr int SA = BM * 8 / 256, SB = BN * 8 / 256;   // octs per thread
    __shared__ unsigned short SM[BM * 64 + BN * 64];
    unsigned short* As = SM;
    unsigned short* Bs = SM + BM * 64;

    const int tid  = threadIdx.x;
    const int wave = tid >> 6, lane = tid & 63;
    const int low  = lane & 15, quad = lane >> 4;
    const int wm   = (wave & 1) * (BM / 2), wn = (wave >> 1) * (BN / 2);

    const int xcd    = blockIdx.x & 7;
    const int within = blockIdx.x >> 3;
    const int rowBlk = xcd * xcdRows + (within % xcdRows);
    const int colBlk = within / xcdRows;
    const int row0 = rowBlk * BM, col0 = colBlk * BN;

    size_t a_src[SA]; int a_dst[SA];
    #pragma unroll
    for (int s = 0; s < SA; ++s) {
        const int p = tid + 256 * s;
        const int m = p >> 3, q = p & 7;
        a_src[s] = (size_t)(row0 + m) * K + q * 8;
        a_dst[s] = m * 64 + (q ^ (m & 7)) * 8;
    }
    size_t b_src[SB]; int b_dst[SB];
    #pragma unroll
    for (int s = 0; s < SB; ++s) {
        const int p = tid + 256 * s;
        const int m = p >> 3, q = p & 7;
        b_src[s] = (size_t)(col0 + m) * K + q * 8;
        b_dst[s] = m * 64 + (q ^ (m & 7)) * 8;
    }

    f32x4 acc[WMT][WNT];
    #pragma unroll
    for (int i = 0; i < WMT; ++i)
        #pragma unroll
        for (int j = 0; j < WNT; ++j) acc[i][j] = (f32x4){0.f, 0.f, 0.f, 0.f};

    bf16x8 ar[SA], br[SB];
    const float*          af32 = (const float*)Asrc;
    const unsigned short* a16  = (const unsigned short*)Asrc;

    #pragma unroll
    for (int s = 0; s < SA; ++s) {
        if (CVT_A) {
            const float4 f0 = *(const float4*)(af32 + a_src[s]);
            const float4 f1 = *(const float4*)(af32 + a_src[s] + 4);
            union { uint4 v; bf16x8 h; } u;
            u.v.x = pack_trunc(f0.x, f0.y); u.v.y = pack_trunc(f0.z, f0.w);
            u.v.z = pack_trunc(f1.x, f1.y); u.v.w = pack_trunc(f1.z, f1.w);
            ar[s] = u.h;
        } else {
            ar[s] = *(const bf16x8*)(a16 + a_src[s]);
        }
    }
    #pragma unroll
    for (int s = 0; s < SB; ++s) br[s] = *(const bf16x8*)(Bt + b_src[s]);

    const int NIT = K >> 6;
    for (int it = 0; it < NIT; ++it) {
        __syncthreads();
        #pragma unroll
        for (int s = 0; s < SA; ++s) *(bf16x8*)&As[a_dst[s]] = ar[s];
        #pragma unroll
        for (int s = 0; s < SB; ++s) *(bf16x8*)&Bs[b_dst[s]] = br[s];
        __syncthreads();

        if (it + 1 < NIT) {
            const int ko = (it + 1) * 64;
            #pragma unroll
            for (int s = 0; s < SA; ++s) {
                if (CVT_A) {
                    const float4 f0 = *(const float4*)(af32 + a_src[s] + ko);
                    const float4 f1 = *(const float4*)(af32 + a_src[s] + ko + 4);
                    union { uint4 v; bf16x8 h; } u;
                    u.v.x = pack_trunc(f0.x, f0.y); u.v.y = pack_trunc(f0.z, f0.w);
                    u.v.z = pack_trunc(f1.x, f1.y); u.v.w = pack_trunc(f1.z, f1.w);
                    ar[s] = u.h;
                } else {
                    ar[s] = *(const bf16x8*)(a16 + a_src[s] + ko);
                }
            }
            #pragma unroll
            for (int s = 0; s < SB; ++s) br[s] = *(const bf16x8*)(Bt + b_src[s] + ko);
        }

        #pragma unroll
        for (int h = 0; h < 2; ++h) {
            bf16x8 af[WMT], bfr[WNT];
            #pragma unroll
            for (int t = 0; t < WMT; ++t)
                af[t] = *(const bf16x8*)
                    &As[(wm + t * 16 + low) * 64 + (((h * 4 + quad) ^ (low & 7)) * 8)];
            #pragma unroll
            for (int t = 0; t < WNT; ++t)
                bfr[t] = *(const bf16x8*)
                    &Bs[(wn + t * 16 + low) * 64 + (((h * 4 + quad) ^ (low & 7)) * 8)];
            #pragma unroll
            for (int i = 0; i < WMT; ++i)
                #pragma unroll
                for (int j = 0; j < WNT; ++j)
                    acc[i][j] = __builtin_amdgcn_mfma_f32_16x16x32_bf16(
                        af[i], bfr[j], acc[i][j], 0, 0, 0);
        }
    }

    float bv[WNT];
    #pragma unroll
    for (int j = 0; j < WNT; ++j) bv[j] = bias[col0 + wn + j * 16 + low];

    const bool isV = (OMODE == 2) && (col0 >= 1024);
    if (isV) {
        // transpose through LDS (reuse SM), two 64-col passes, coalesced stores
        unsigned short (*Cs)[130] = (unsigned short (*)[130])SM;   // [64 d][128 t + pad]
        const int bI = row0 >> 11;
        const int t0 = row0 & 2047;
        const int dloc = tid >> 2, sub = tid & 3;
        __syncthreads();                        // done reading As/Bs
        #pragma unroll
        for (int p = 0; p < 2; ++p) {
            if ((wave >> 1) == p) {
                #pragma unroll
                for (int i = 0; i < WMT; ++i)
                    #pragma unroll
                    for (int j = 0; j < WNT; ++j)
                        #pragma unroll
                        for (int r = 0; r < 4; ++r)
                            Cs[j * 16 + low][wm + i * 16 + quad * 4 + r] =
                                f2bf(acc[i][j][r] + bv[j]);
            }
            __syncthreads();
            const int dglob = col0 - 1024 + p * 64 + dloc;
            unsigned short* vb =
                Cv + (((size_t)(bI * 512 + dglob)) << 11) + t0 + sub * 8;
            #pragma unroll
            for (int e = 0; e < 4; ++e)
                *(bf16x8*)(vb + e * 32) = *(const bf16x8*)&Cs[dloc][e * 32 + sub * 8];
            __syncthreads();
        }
    } else {
        #pragma unroll
        for (int i = 0; i < WMT; ++i)
            #pragma unroll
            for (int r = 0; r < 4; ++r) {
                const int row = row0 + wm + i * 16 + quad * 4 + r;
                #pragma unroll
                for (int j = 0; j < WNT; ++j) {
                    const int col = col0 + wn + j * 16 + low;
                    const float v = acc[i][j][r] + bv[j];
                    if (OMODE == 0)
                        ((float*)C)[(size_t)row * N + col] = v;
                    else if (OMODE == 1)
                        ((unsigned short*)C)[(size_t)row * N + col] = f2bf(v);
                    else
                        ((unsigned short*)C)[(size_t)row * QK_LD + col] = f2bf(v);
                }
            }
    }
}

// ---------------------------------------------------------------------------
// attention v4: wave-split-K, P-in-registers (R2-verified algebra), K/V
// staged ONCE per block in LDS via global_load_lds DMA (v1-proven pattern).
//   Ks[k][8 slots]: slot s holds d-oct (s ^ hk(k)), hk(k)=(k&3)|(((k>>3)&1)<<2)
//   Vs[d][8 slots]: slot s holds k-oct (s ^ hv(d)), hv same formula
//   => permuted-row K A-frag reads and vT-layout V B-frag reads are both
//      2-way-conflict-free ds_read_b128 (uniform 8 dwords/bank).
// Register contents after LDS reads are bit-identical to R2's global loads.
// ---------------------------------------------------------------------------
template<bool MASK>
__device__ __forceinline__ void qk_step(
    const bf16x8 k00, const bf16x8 k01, const bf16x8 k10, const bf16x8 k11,
    const bf16x8 (&qf)[2][2], bf16x8 (&pf)[2], float (&lp)[2],
    const int qrel0, const int koffb)
{
    #pragma unroll
    for (int qb = 0; qb < 2; ++qb) {
        f32x4 s0 = (f32x4){0.f, 0.f, 0.f, 0.f};
        f32x4 s1 = (f32x4){0.f, 0.f, 0.f, 0.f};
        s0 = __builtin_amdgcn_mfma_f32_16x16x32_bf16(k00, qf[qb][0], s0, 0, 0, 0);
        s0 = __builtin_amdgcn_mfma_f32_16x16x32_bf16(k01, qf[qb][1], s0, 0, 0, 0);
        s1 = __builtin_amdgcn_mfma_f32_16x16x32_bf16(k10, qf[qb][0], s1, 0, 0, 0);
        s1 = __builtin_amdgcn_mfma_f32_16x16x32_bf16(k11, qf[qb][1], s1, 0, 0, 0);
        float p[8];
        #pragma unroll
        for (int r = 0; r < 4; ++r) {
            float v0 = s0[r], v1 = s1[r];
            if (MASK) {
                const int qrel = qrel0 + qb * 16;
                if (koffb + r     > qrel) v0 = -1e30f;   // exp2 -> 0
                if (koffb + r + 4 > qrel) v1 = -1e30f;
            }
            p[r]     = __builtin_amdgcn_exp2f(v0);
            p[r + 4] = __builtin_amdgcn_exp2f(v1);
        }
        // truncate to the exact bf16 values used by the PV MFMA, so l == sum(P_bf16)
        #pragma unroll
        for (int e = 0; e < 8; ++e) {
            union { float f; unsigned u; } c; c.f = p[e];
            c.u &= 0xFFFF0000u; p[e] = c.f;
        }
        lp[qb] += ((p[0] + p[1]) + (p[2] + p[3])) + ((p[4] + p[5]) + (p[6] + p[7]));
        union { uint4 v; bf16x8 h; } u;
        u.v.x = pack_trunc(p[0], p[1]); u.v.y = pack_trunc(p[2], p[3]);
        u.v.z = pack_trunc(p[4], p[5]); u.v.w = pack_trunc(p[6], p[7]);
        pf[qb] = u.h;
    }
}

__global__ __launch_bounds__(256, 2) void attn_mfma(
    const unsigned short* __restrict__ qk,    // bf16 [8192][1024]  (Q | K)
    const unsigned short* __restrict__ vT,    // bf16 [4*512][2048] (V transposed)
    unsigned short* __restrict__ y)           // bf16 [8192][512]
{
    const int bh  = blockIdx.x & 31;          // same-bh blocks -> same XCD
    const int pa  = blockIdx.x >> 5;          // 0..15
    const int b   = bh >> 3, h = bh & 7;
    const int qA0 = pa * 64;
    const int qB0 = (31 - pa) * 64;
    const int nA  = pa + 1, nB = 32 - pa;
    const int tid = threadIdx.x;
    const int wave = tid >> 6, lane = tid & 63;
    const int low  = lane & 15, quad = lane >> 4;
    const int kh   = wave & 1, qh = wave >> 1;

    __shared__ char smem[34816];
    unsigned short* KsB = (unsigned short*)smem;           // [2][4096] shorts
    unsigned short* VsB = (unsigned short*)smem + 8192;    // [2][4096] shorts

    const size_t base = (size_t)b * SEQ_T * QK_LD + h * 64;
    const unsigned short* qp = qk + base;
    const unsigned short* kp = qk + base + 512;
    const unsigned short* vp = vT + ((size_t)(b * 512 + h * 64) << 11);

    // Q fragments [side][qb][dh], scaled once (R2-proven)
    bf16x8 qf[2][2][2];
    #pragma unroll
    for (int s = 0; s < 2; ++s) {
        const int q0 = (s ? qB0 : qA0) + qh * 32;
        #pragma unroll
        for (int qb = 0; qb < 2; ++qb) {
            const size_t qr = (size_t)(q0 + qb * 16 + low) * QK_LD;
            #pragma unroll
            for (int dh = 0; dh < 2; ++dh)
                qf[s][qb][dh] = scale_frag(
                    *(const bf16x8*)(qp + qr + dh * 32 + quad * 8), CL);
        }
    }

    // ---- staging addresses (per-lane constants) ----
    const int r8 = lane >> 3, s8 = lane & 7;           // 8 rows x 8 slots per instr
    // slot hash h(row) = (row&3) | (((row>>3)&1)<<2); row = wave*16 + ii*8 + r8
    const unsigned short* ksrc[2]; const unsigned short* vsrc[2]; int dst[2];
    #pragma unroll
    for (int ii = 0; ii < 2; ++ii) {
        const int hs = (r8 & 3) | (ii << 2);
        ksrc[ii] = kp + (size_t)(wave * 16 + ii * 8 + r8) * QK_LD + (s8 ^ hs) * 8;
        vsrc[ii] = vp + ((size_t)(wave * 16 + ii * 8 + r8) << 11) + (s8 ^ hs) * 8;
        dst[ii]  = (wave * 16 + ii * 8) * 64;
    }

    // ---- fragment read offsets (per-lane constants, in shorts) ----
    const int hkv = (low & 3) | (((low >> 2) & 1) << 2);
    const int hvv = (low & 3) | ((low >> 3) << 2);
    const int krow0 = kh * 32 + ((low >> 2) << 3) + (low & 3);   // rowperm
    const int koffK[2][2] = {
        { krow0 * 64 + ((quad    ) ^ hkv) * 8, krow0 * 64 + ((quad + 4) ^ hkv) * 8 },
        { (krow0+4)*64 + ((quad  ) ^ hkv) * 8, (krow0+4)*64 + ((quad + 4) ^ hkv) * 8 } };
    int voff[4];
    #pragma unroll
    for (int t = 0; t < 4; ++t)
        voff[t] = (t * 16 + low) * 64 + ((kh * 4 + quad) ^ hvv) * 8;
    const int koffb = kh * 32 + quad * 8;              // lane's k base (masks/PV)

    // prologue: stage tile 0
    #pragma unroll
    for (int ii = 0; ii < 2; ++ii) {
        gl_lds16(ksrc[ii], KsB + dst[ii]);
        gl_lds16(vsrc[ii], VsB + dst[ii]);
    }

    f32x4 o[2][2][4];
    #pragma unroll
    for (int s = 0; s < 2; ++s)
        #pragma unroll
        for (int qb = 0; qb < 2; ++qb)
            #pragma unroll
            for (int t = 0; t < 4; ++t) o[s][qb][t] = (f32x4){0.f, 0.f, 0.f, 0.f};
    float lp[2][2] = {{0.f, 0.f}, {0.f, 0.f}};

    __syncthreads();   // tile 0 staged (compiler drains vmcnt before barrier)

    for (int kc = 0; kc < nB; ++kc) {
        const int cur = kc & 1;
        if (kc + 1 < nB) {   // DMA next tile into other buffer
            const size_t kadv = (size_t)(kc + 1) * 64 * QK_LD;
            const int    vadv = (kc + 1) * 64;
            const int    db   = (cur ^ 1) * 4096;
            #pragma unroll
            for (int ii = 0; ii < 2; ++ii) {
                gl_lds16(ksrc[ii] + kadv, KsB + db + dst[ii]);
                gl_lds16(vsrc[ii] + vadv, VsB + db + dst[ii]);
            }
        }

        const unsigned short* Kc = KsB + cur * 4096;
        const unsigned short* Vc = VsB + cur * 4096;
        bf16x8 kf[2][2], vf[4];
        #pragma unroll
        for (int kt = 0; kt < 2; ++kt)
            #pragma unroll
            for (int dh = 0; dh < 2; ++dh)
                kf[kt][dh] = *(const bf16x8*)&Kc[koffK[kt][dh]];
        #pragma unroll
        for (int t = 0; t < 4; ++t)
            vf[t] = *(const bf16x8*)&Vc[voff[t]];

        const int kc64 = kc * 64;
        bf16x8 pA[2], pB[2];
        const bool doA = (kc < nA);
        if (doA) {
            const int qrelA = qA0 + qh * 32 + low - kc64;
            if (kc == nA - 1)
                qk_step<true >(kf[0][0], kf[0][1], kf[1][0], kf[1][1], qf[0], pA, lp[0], qrelA, koffb);
            else
                qk_step<false>(kf[0][0], kf[0][1], kf[1][0], kf[1][1], qf[0], pA, lp[0], qrelA, koffb);
        }
        {
            const int qrelB = qB0 + qh * 32 + low - kc64;
            if (kc == nB - 1)
                qk_step<true >(kf[0][0], kf[0][1], kf[1][0], kf[1][1], qf[1], pB, lp[1], qrelB, koffb);
            else
                qk_step<false>(kf[0][0], kf[0][1], kf[1][0], kf[1][1], qf[1], pB, lp[1], qrelB, koffb);
        }

        if (doA) {
            #pragma unroll
            for (int t = 0; t < 4; ++t) {
                o[0][0][t] = __builtin_amdgcn_mfma_f32_16x16x32_bf16(pA[0], vf[t], o[0][0][t], 0, 0, 0);
                o[0][1][t] = __builtin_amdgcn_mfma_f32_16x16x32_bf16(pA[1], vf[t], o[0][1][t], 0, 0, 0);
            }
        }
        #pragma unroll
        for (int t = 0; t < 4; ++t) {
            o[1][0][t] = __builtin_amdgcn_mfma_f32_16x16x32_bf16(pB[0], vf[t], o[1][0][t], 0, 0, 0);
            o[1][1][t] = __builtin_amdgcn_mfma_f32_16x16x32_bf16(pB[1], vf[t], o[1][1][t], 0, 0, 0);
        }

        __syncthreads();   // frag reads done + next-tile DMA drained
    }

    // ---- epilogue: cross-wave (kh) reduction of o and l (R2-proven) ----
    // reuse smem: oB = 2*64*66 f32 (33792B), lB = 2*2*64 f32 (1024B)
    float* oB = (float*)smem;
    float* lB = (float*)(smem + 33792);

    #pragma unroll
    for (int s = 0; s < 2; ++s)
        #pragma unroll
        for (int qb = 0; qb < 2; ++qb) {
            float v = lp[s][qb];
            v += __shfl_xor(v, 16);     // reduce over quads
            v += __shfl_xor(v, 32);
            if (quad == 0) lB[(kh * 2 + qh) * 64 + (s * 2 + qb) * 16 + low] = v;
        }
    if (kh == 1) {
        #pragma unroll
        for (int s = 0; s < 2; ++s)
            #pragma unroll
            for (int qb = 0; qb < 2; ++qb)
                #pragma unroll
                for (int t = 0; t < 4; ++t)
                    #pragma unroll
                    for (int r = 0; r < 4; ++r)
                        oB[qh * 4224 + ((s * 2 + qb) * 16 + quad * 4 + r) * 66
                           + low + t * 16] = o[s][qb][t][r];
    }
    __syncthreads();
    if (kh == 0) {
        #pragma unroll
        for (int s = 0; s < 2; ++s) {
            const int q0 = (s ? qB0 : qA0) + qh * 32;
            #pragma unroll
            for (int qb = 0; qb < 2; ++qb) {
                #pragma unroll
                for (int r = 0; r < 4; ++r) {
                    const int ri = (s * 2 + qb) * 16 + quad * 4 + r;
                    const float l = lB[qh * 64 + ri] + lB[128 + qh * 64 + ri];
                    const float rl = 1.f / l;
                    const int qrow = q0 + qb * 16 + quad * 4 + r;
                    unsigned short* yp =
                        y + (size_t)(b * SEQ_T + qrow) * N_EMBD + h * 64 + low;
                    #pragma unroll
                    for (int t = 0; t < 4; ++t)
                        yp[t * 16] = f2bf(
                            (o[s][qb][t][r] + oB[qh * 4224 + ri * 66 + low + t * 16]) * rl);
                }
            }
        }
    }
}

// ---------------------------------------------------------------------------
extern "C" void kernel_launch(void* const* d_in, const int* in_sizes, int n_in,
                              void* d_out, int out_size, void* d_ws, size_t ws_size,
                              hipStream_t stream)
{
    const float* x      = (const float*)d_in[0];
    const float* attn_w = (const float*)d_in[1];   // [512][1536]
    const float* attn_b = (const float*)d_in[2];
    const float* proj_w = (const float*)d_in[3];   // [512][512]
    const float* proj_b = (const float*)d_in[4];
    float*       out    = (float*)d_out;

    char* ws = (char*)d_ws;
    unsigned short* qk_bf = (unsigned short*)(ws);                       // 16.78 MB
    unsigned short* vT    = (unsigned short*)(ws + 16777216);            //  8.39 MB
    unsigned short* y_bf  = (unsigned short*)(ws + 25165824);            //  8.39 MB
    unsigned short* w1t   = (unsigned short*)(ws + 33554432);            //  1.57 MB
    unsigned short* w2t   = (unsigned short*)(ws + 35127296);            //  0.52 MB

    prep<<<1024, 256, 0, stream>>>(attn_w, w1t, proj_w, w2t);

    // qkv = x(fp32, converted in-staging) @ w1t^T + b ; Q/K -> qk_bf, V -> vT
    gemm_mfma<128, 128, true, 2><<<dim3(768), 256, 0, stream>>>(
        x, w1t, attn_b, qk_bf, vT, 1536, N_EMBD, 8);

    attn_mfma<<<dim3(512), 256, 0, stream>>>(qk_bf, vT, y_bf);

    gemm_mfma<64, 128, false, 0><<<dim3(512), 256, 0, stream>>>(
        y_bf, w2t, proj_b, out, nullptr, N_EMBD, N_EMBD, 16);
}